// Round 1
// baseline (443.703 us; speedup 1.0000x reference)
//
#include <hip/hip_runtime.h>
#include <hip/hip_bf16.h>

// NeighborlistVerletNsq: all-unique-pairs minimum-image displacement + distance
// + verlet-build / cutoff masks on MI355X.
//
// N = 6144 particles, P = N(N-1)/2 = 18,871,296 pairs.
// Output layout (flat f32, concatenated in reference return order):
//   [0,      3P)  r_ij  (row-major [P,3])
//   [3P,     4P)  d_ij
//   [4P,     5P)  in_build  (1.0f / 0.0f)
//   [5P,     6P)  in_cutoff (1.0f / 0.0f)

#define NPART 6144
#define PAIRS ((NPART * (NPART - 1)) / 2)   // 18,871,296  (fits int32)

// Replicates jnp.remainder(t, L) then -half, bitwise in fp32, for the
// restricted domain t in (-L/2, 3L/2) that holds because positions in [0, L):
//   fmod(t,L) = t-L  (t >= L; Sterbenz-exact subtraction)
//             = t    (0 <= t < L)
//             = t    (t < 0), then remainder-adjust adds L in fp32.
__device__ __forceinline__ float min_image(float diff, float L, float half) {
    float t = __fadd_rn(diff, half);
    float m = t;
    if (t >= L)      m = __fsub_rn(t, L);
    else if (t < 0.f) m = __fadd_rn(t, L);
    return __fsub_rn(m, half);
}

__global__ __launch_bounds__(256) void nsq_pairs_kernel(
    const float* __restrict__ pos,   // [N,3]
    const float* __restrict__ box,   // [3,3] diagonal
    float* __restrict__ out)
{
    int p = blockIdx.x * blockDim.x + threadIdx.x;
    if (p >= PAIRS) return;

    // ---- invert p -> (i, j), i < j, np.triu_indices order ----
    // row_start(i) = i*N - i*(i+1)/2 ; i = floor((A - sqrt(A^2 - 8p)) / 2), A = 2N-1
    const double A = (double)(2 * NPART - 1);
    double disc = A * A - 8.0 * (double)p;
    int i = (int)((A - sqrt(disc)) * 0.5);
    i = max(0, min(i, NPART - 2));
    int rs = i * NPART - (i * (i + 1)) / 2;       // row_start(i)
    int rlen = NPART - 1 - i;                     // row length of row i
    // fixups (double sqrt can be off by one at row boundaries)
    while (p >= rs + rlen) { rs += rlen; ++i; rlen = NPART - 1 - i; }
    while (p < rs)         { rs -= (NPART - i); --i; rlen = NPART - 1 - i; }
    int j = i + 1 + (p - rs);

    // ---- load positions (tiny, L1/L2 resident) and box lengths ----
    float xi = pos[3 * i + 0], yi = pos[3 * i + 1], zi = pos[3 * i + 2];
    float xj = pos[3 * j + 0], yj = pos[3 * j + 1], zj = pos[3 * j + 2];
    float Lx = box[0], Ly = box[4], Lz = box[8];
    float hx = __fmul_rn(Lx, 0.5f);
    float hy = __fmul_rn(Ly, 0.5f);
    float hz = __fmul_rn(Lz, 0.5f);

    // ---- minimum-image displacement (bitwise == jnp.remainder path) ----
    float rx = min_image(__fsub_rn(xi, xj), Lx, hx);
    float ry = min_image(__fsub_rn(yi, yj), Ly, hy);
    float rz = min_image(__fsub_rn(zi, zj), Lz, hz);

    // ---- distance: ((rx^2 + ry^2) + rz^2), no FMA contraction ----
    float s = __fadd_rn(__fadd_rn(__fmul_rn(rx, rx), __fmul_rn(ry, ry)),
                        __fmul_rn(rz, rz));
    float d = sqrtf(s);

    // ---- stores (all regions lane-contiguous -> coalesced) ----
    const int P = PAIRS;
    out[3 * p + 0] = rx;
    out[3 * p + 1] = ry;
    out[3 * p + 2] = rz;
    out[3 * P + p] = d;
    out[4 * P + p] = (d <  0.6f) ? 1.0f : 0.0f;   // CUTOFF + SKIN as f32
    out[5 * P + p] = (d <= 0.5f) ? 1.0f : 0.0f;   // CUTOFF
}

extern "C" void kernel_launch(void* const* d_in, const int* in_sizes, int n_in,
                              void* d_out, int out_size, void* d_ws, size_t ws_size,
                              hipStream_t stream) {
    const float* pos = (const float*)d_in[0];   // [6144, 3] f32
    const float* box = (const float*)d_in[1];   // [3, 3]  f32
    float* out = (float*)d_out;                 // 6P f32

    const int block = 256;
    const int grid = (PAIRS + block - 1) / block;  // 73,716 blocks
    nsq_pairs_kernel<<<grid, block, 0, stream>>>(pos, box, out);
}